// Round 3
// baseline (478.624 us; speedup 1.0000x reference)
//
#include <hip/hip_runtime.h>

#define HEADS 16
#define HD 64
#define ROT 32
#define SEQ 4096
#define BROWS 256
#define PADW 33   // half-row stride in floats (32 data + 1 pad)

// ---------------------------------------------------------------------------
// Setup: build the combined 64x64 matrix Wp = (B1*...*B32) @ r_matrix,
// with columns pre-permuted for RoPE: Wp[:,n] = W[:,2n] (n<32), W[:,2n-63] (n>=32).
// 1 block, 64 threads; thread t owns row t. Rows are independent -> no barriers.
// ---------------------------------------------------------------------------
__global__ void build_W_kernel(const float* __restrict__ thetas,
                               const float* __restrict__ theta_scale,
                               const float* __restrict__ r_matrix,
                               const int* __restrict__ pairs,
                               float* __restrict__ Wp) {
    __shared__ float M[64][65];
    const int t = threadIdx.x;  // 0..63
    for (int k = 0; k < 64; ++k) M[t][k] = (k == t) ? 1.0f : 0.0f;
    const float scale = theta_scale[0];
    #pragma unroll 1
    for (int r = 0; r < ROT; ++r) {
        const int i = pairs[2 * r + 0];
        const int j = pairs[2 * r + 1];
        const float th = thetas[r] * scale;
        float s, c;
        sincosf(th, &s, &c);
        const float xi = M[t][i];
        const float xj = M[t][j];
        const float gi =  xi * c + xj * s;
        const float gj = -xi * s + xj * c;
        const float ni = (2.0f * gi + xi - 2.0f * gi * c) / 3.0f;
        const float nj = (2.0f * gj + xj - 2.0f * gi * s) / 3.0f;
        M[t][i] = ni;
        M[t][j] = nj;
    }
    #pragma unroll 1
    for (int n = 0; n < 64; ++n) {
        const int col = (n < 32) ? (2 * n) : (2 * (n - 32) + 1);
        float acc = 0.0f;
        for (int k = 0; k < 64; ++k) acc = fmaf(M[t][k], r_matrix[k * 64 + col], acc);
        Wp[t * 64 + n] = acc;
    }
}

// ---------------------------------------------------------------------------
// Main fused kernel: out_row = RoPE_s( x_row @ Wp ).
// 256 threads = 256 rows per block (16 seq positions x 16 heads).
// x staged through LDS in 32-col halves (coalesced global, conflict-free LDS).
// Wp accessed with wave-uniform addresses -> scalar loads (SGPR FMA operands).
// ---------------------------------------------------------------------------
__global__ __launch_bounds__(256, 4) void fused_main(
    const float* __restrict__ x,
    const float* __restrict__ Wp,
    const float* __restrict__ inv_freq,
    float* __restrict__ out)
{
    __shared__ float xs[BROWS * PADW];   // 33,792 B
    __shared__ float tc[16 * 33];        // cos table, 2,112 B
    __shared__ float tsn[16 * 33];       // sin table, 2,112 B

    const int tid = threadIdx.x;
    const int blk = blockIdx.x;
    const long long base4 = (long long)blk * (BROWS * HD / 4);  // float4 offset of tile
    const float4* __restrict__ xv = (const float4*)x + base4;
    float4* __restrict__ ov = (float4*)out + base4;

    // trig table for this block's 16 sequence positions (s0 = (blk % 256) * 16)
    {
        const int s0 = (blk & (SEQ / 16 - 1)) * 16;
        #pragma unroll
        for (int u = 0; u < 2; ++u) {
            const int e = tid * 2 + u;          // 0..511
            const int sl = e >> 5;              // 0..15
            const int f = e & 31;               // 0..31
            const float ang = (float)(s0 + sl) * inv_freq[f];
            float sn, cs;
            sincosf(ang, &sn, &cs);
            tc[sl * 33 + f] = cs;
            tsn[sl * 33 + f] = sn;
        }
    }

    float acc[64];
    #pragma unroll
    for (int n = 0; n < 64; ++n) acc[n] = 0.0f;

    #pragma unroll 1
    for (int half = 0; half < 2; ++half) {
        __syncthreads();  // half 0: makes trig visible; half 1: prior xs readers done
        // stage 256 rows x 32 cols (cols [half*32, half*32+32) )
        #pragma unroll
        for (int it = 0; it < 8; ++it) {
            const int f = it * 256 + tid;   // 0..2047
            const int row = f >> 3;
            const int c4 = f & 7;
            const float4 v = xv[row * 16 + half * 8 + c4];
            float* p = &xs[row * PADW + c4 * 4];
            p[0] = v.x; p[1] = v.y; p[2] = v.z; p[3] = v.w;
        }
        __syncthreads();

        const float* xrow = &xs[tid * PADW];
        #pragma unroll 1
        for (int kc = 0; kc < 2; ++kc) {
            float xk[16];
            #pragma unroll
            for (int m = 0; m < 16; ++m) xk[m] = xrow[kc * 16 + m];
            const int kbase = half * 32 + kc * 16;
            #pragma unroll
            for (int m = 0; m < 16; ++m) {
                const float4* __restrict__ w4 = (const float4*)&Wp[(kbase + m) * 64];
                #pragma unroll
                for (int n4 = 0; n4 < 16; ++n4) {
                    const float4 w = w4[n4];   // wave-uniform -> s_load
                    acc[n4 * 4 + 0] = fmaf(xk[m], w.x, acc[n4 * 4 + 0]);
                    acc[n4 * 4 + 1] = fmaf(xk[m], w.y, acc[n4 * 4 + 1]);
                    acc[n4 * 4 + 2] = fmaf(xk[m], w.z, acc[n4 * 4 + 2]);
                    acc[n4 * 4 + 3] = fmaf(xk[m], w.w, acc[n4 * 4 + 3]);
                }
            }
        }
    }

    // RoPE combine (in place): acc[0..31] = even cols, acc[32..63] = odd cols
    {
        const int sl = tid >> 4;
        #pragma unroll
        for (int n = 0; n < 32; ++n) {
            const float c = tc[sl * 33 + n];
            const float s = tsn[sl * 33 + n];
            const float a = acc[n];
            const float b = acc[32 + n];
            acc[n]      = a * c - b * s;
            acc[32 + n] = a * s + b * c;
        }
    }

    // write back through LDS for coalesced stores, in two 32-col halves
    #pragma unroll 1
    for (int half = 0; half < 2; ++half) {
        __syncthreads();  // prior xs readers done
        float* prow = &xs[tid * PADW];
        #pragma unroll
        for (int n = 0; n < 32; ++n) prow[n] = acc[half * 32 + n];
        __syncthreads();
        #pragma unroll
        for (int it = 0; it < 8; ++it) {
            const int f = it * 256 + tid;
            const int row = f >> 3;
            const int c4 = f & 7;
            const float* p = &xs[row * PADW + c4 * 4];
            ov[row * 16 + half * 8 + c4] = make_float4(p[0], p[1], p[2], p[3]);
        }
    }
}

extern "C" void kernel_launch(void* const* d_in, const int* in_sizes, int n_in,
                              void* d_out, int out_size, void* d_ws, size_t ws_size,
                              hipStream_t stream) {
    const float* x   = (const float*)d_in[0];
    const float* th  = (const float*)d_in[1];
    const float* sc  = (const float*)d_in[2];
    const float* R   = (const float*)d_in[3];
    const float* ivf = (const float*)d_in[4];
    const int*   pr  = (const int*)d_in[5];
    float* W = (float*)d_ws;   // 64*64 floats = 16 KB scratch

    build_W_kernel<<<1, 64, 0, stream>>>(th, sc, R, pr, W);

    const int rows = out_size / HD;        // 524,288
    const int blocks = rows / BROWS;       // 2,048
    fused_main<<<blocks, 256, 0, stream>>>(x, W, ivf, (float*)d_out);
}

// Round 4
// 342.607 us; speedup vs baseline: 1.3970x; 1.3970x over previous
//
#include <hip/hip_runtime.h>

#define HEADS 16
#define HD 64
#define ROT 32
#define SEQ 4096
#define BROWS 256
#define PADW 33   // half-row stride in floats (32 data + 1 pad)

typedef float sv16 __attribute__((ext_vector_type(16)));

// ---------------------------------------------------------------------------
// Setup: build Wp[k][n] = sum_j M[k][j] * R[j][perm(n)], perm(n)=2n / 2(n-32)+1.
// M = product of the 32 blended-Givens column updates applied to I.
// 256 threads: R staged to LDS coalesced; wave 0 runs the serial rotation
// (each thread owns one row of M -> no barriers inside); 256-thread matmul.
// ---------------------------------------------------------------------------
__global__ __launch_bounds__(256) void build_W_kernel(
    const float* __restrict__ thetas,
    const float* __restrict__ theta_scale,
    const float* __restrict__ r_matrix,
    const int* __restrict__ pairs,
    float* __restrict__ Wp)
{
    __shared__ float M[64][65];
    __shared__ float Rl[64][65];
    const int tid = threadIdx.x;

    // stage r_matrix (4096 floats) coalesced
    #pragma unroll
    for (int it = 0; it < 16; ++it) {
        const int f = it * 256 + tid;
        Rl[f >> 6][f & 63] = r_matrix[f];
    }

    if (tid < 64) {
        const int t = tid;
        #pragma unroll
        for (int k = 0; k < 64; ++k) M[t][k] = (k == t) ? 1.0f : 0.0f;
        const float scale = theta_scale[0];
        #pragma unroll 1
        for (int r = 0; r < ROT; ++r) {
            const int i = pairs[2 * r + 0];
            const int j = pairs[2 * r + 1];
            const float th = thetas[r] * scale;
            float s, c;
            sincosf(th, &s, &c);
            const float xi = M[t][i];
            const float xj = M[t][j];
            const float gi =  xi * c + xj * s;
            const float gj = -xi * s + xj * c;
            const float ni = (2.0f * gi + xi - 2.0f * gi * c) / 3.0f;
            const float nj = (2.0f * gj + xj - 2.0f * gi * s) / 3.0f;
            M[t][i] = ni;
            M[t][j] = nj;
        }
    }
    __syncthreads();

    // Wp[k][n]: thread (kq = tid>>6, n = tid&63) computes 16 k's for its n.
    const int n = tid & 63;
    const int kq = tid >> 6;
    const int cn = (n < 32) ? (2 * n) : (2 * (n - 32) + 1);
    #pragma unroll 1
    for (int kk = 0; kk < 16; ++kk) {
        const int k = kq * 16 + kk;
        float acc = 0.0f;
        #pragma unroll
        for (int j = 0; j < 64; ++j) acc = fmaf(M[k][j], Rl[j][cn], acc);
        Wp[k * 64 + n] = acc;   // wave-coalesced 256B store
    }
}

// ---------------------------------------------------------------------------
// Main fused kernel: out_row = RoPE_s( x_row @ Wp ).
// 256 threads = 256 rows per block. x staged via LDS (coalesced), W rows
// pulled through the SCALAR pipe (s_load_dwordx16) so weights live in SGPRs:
// acc[64] stays in VGPRs (~95 total), no scratch spill.
// ---------------------------------------------------------------------------
__global__ __launch_bounds__(256, 4) void fused_main(
    const float* __restrict__ x,
    const float* __restrict__ Wp,
    const float* __restrict__ inv_freq,
    float* __restrict__ out)
{
    __shared__ float xs[BROWS * PADW];   // 33,792 B
    __shared__ float tc[16 * 33];        // cos table
    __shared__ float tsn[16 * 33];       // sin table

    const int tid = threadIdx.x;
    const int blk = blockIdx.x;
    const long long base4 = (long long)blk * (BROWS * HD / 4);
    const float4* __restrict__ xv = (const float4*)x + base4;
    float4* __restrict__ ov = (float4*)out + base4;

    // trig table for this block's 16 sequence positions
    {
        const int s0 = (blk & (SEQ / 16 - 1)) * 16;
        #pragma unroll
        for (int u = 0; u < 2; ++u) {
            const int e = tid * 2 + u;
            const int sl = e >> 5;
            const int f = e & 31;
            const float ang = (float)(s0 + sl) * inv_freq[f];
            float sn, cs;
            sincosf(ang, &sn, &cs);
            tc[sl * 33 + f] = cs;
            tsn[sl * 33 + f] = sn;
        }
    }

    float acc[64];
    #pragma unroll
    for (int nn = 0; nn < 64; ++nn) acc[nn] = 0.0f;

    #pragma unroll 1
    for (int half = 0; half < 2; ++half) {
        __syncthreads();
        #pragma unroll
        for (int it = 0; it < 8; ++it) {
            const int f = it * 256 + tid;
            const int row = f >> 3;
            const int c4 = f & 7;
            const float4 v = xv[row * 16 + half * 8 + c4];
            float* p = &xs[row * PADW + c4 * 4];
            p[0] = v.x; p[1] = v.y; p[2] = v.z; p[3] = v.w;
        }
        __syncthreads();

        const float* xrow = &xs[tid * PADW];
        #pragma unroll 1
        for (int kc = 0; kc < 2; ++kc) {
            float xk[16];
            #pragma unroll
            for (int m = 0; m < 16; ++m) xk[m] = xrow[kc * 16 + m];
            const int kbase = half * 32 + kc * 16;
            #pragma unroll
            for (int m = 0; m < 16; ++m) {
                // W row (kbase+m): 64 floats via the scalar pipe -> SGPRs
                const float* pm = Wp + (kbase + m) * 64;   // uniform address
                sv16 w0, w1, w2, w3;
                asm volatile(
                    "s_load_dwordx16 %0, %4, 0x0\n\t"
                    "s_load_dwordx16 %1, %4, 0x40\n\t"
                    "s_load_dwordx16 %2, %4, 0x80\n\t"
                    "s_load_dwordx16 %3, %4, 0xC0\n\t"
                    "s_waitcnt lgkmcnt(0)"
                    : "=&s"(w0), "=&s"(w1), "=&s"(w2), "=&s"(w3)
                    : "s"(pm));
                const float xm = xk[m];
                #pragma unroll
                for (int i = 0; i < 16; ++i) {
                    acc[i]      = fmaf(xm, w0[i], acc[i]);
                    acc[16 + i] = fmaf(xm, w1[i], acc[16 + i]);
                    acc[32 + i] = fmaf(xm, w2[i], acc[32 + i]);
                    acc[48 + i] = fmaf(xm, w3[i], acc[48 + i]);
                }
            }
        }
    }

    // RoPE combine: acc[0..31] = even cols, acc[32..63] = odd cols
    {
        const int sl = tid >> 4;
        #pragma unroll
        for (int n = 0; n < 32; ++n) {
            const float c = tc[sl * 33 + n];
            const float s = tsn[sl * 33 + n];
            const float a = acc[n];
            const float b = acc[32 + n];
            acc[n]      = a * c - b * s;
            acc[32 + n] = a * s + b * c;
        }
    }

    // write back through LDS for coalesced stores, in two 32-col halves
    #pragma unroll 1
    for (int half = 0; half < 2; ++half) {
        __syncthreads();
        float* prow = &xs[tid * PADW];
        #pragma unroll
        for (int n = 0; n < 32; ++n) prow[n] = acc[half * 32 + n];
        __syncthreads();
        #pragma unroll
        for (int it = 0; it < 8; ++it) {
            const int f = it * 256 + tid;
            const int row = f >> 3;
            const int c4 = f & 7;
            const float* p = &xs[row * PADW + c4 * 4];
            ov[row * 16 + half * 8 + c4] = make_float4(p[0], p[1], p[2], p[3]);
        }
    }
}

extern "C" void kernel_launch(void* const* d_in, const int* in_sizes, int n_in,
                              void* d_out, int out_size, void* d_ws, size_t ws_size,
                              hipStream_t stream) {
    const float* x   = (const float*)d_in[0];
    const float* th  = (const float*)d_in[1];
    const float* sc  = (const float*)d_in[2];
    const float* R   = (const float*)d_in[3];
    const float* ivf = (const float*)d_in[4];
    const int*   pr  = (const int*)d_in[5];
    float* W = (float*)d_ws;   // 64*64 floats = 16 KB scratch

    build_W_kernel<<<1, 256, 0, stream>>>(th, sc, R, pr, W);

    const int rows = out_size / HD;        // 524,288
    const int blocks = rows / BROWS;       // 2,048
    fused_main<<<blocks, 256, 0, stream>>>(x, W, ivf, (float*)d_out);
}

// Round 5
// 285.583 us; speedup vs baseline: 1.6760x; 1.1997x over previous
//
#include <hip/hip_runtime.h>

#define HEADS 16
#define HD 64
#define ROT 32
#define SEQ 4096
#define BROWS 256
#define PADW 33   // half-row stride in floats (32 data + 1 pad)

typedef float sv16 __attribute__((ext_vector_type(16)));

// ---------------------------------------------------------------------------
// Setup: build Wp[k][n] = sum_j M[k][j] * R[j][perm(n)], perm(n)=2n / 2(n-32)+1.
// M = product of the 32 blended-Givens column updates applied to I.
// 256 threads: R staged to LDS coalesced; wave 0 runs the serial rotation
// (each thread owns one row of M -> no barriers inside); 256-thread matmul.
// ---------------------------------------------------------------------------
__global__ __launch_bounds__(256) void build_W_kernel(
    const float* __restrict__ thetas,
    const float* __restrict__ theta_scale,
    const float* __restrict__ r_matrix,
    const int* __restrict__ pairs,
    float* __restrict__ Wp)
{
    __shared__ float M[64][65];
    __shared__ float Rl[64][65];
    const int tid = threadIdx.x;

    // stage r_matrix (4096 floats) coalesced
    #pragma unroll
    for (int it = 0; it < 16; ++it) {
        const int f = it * 256 + tid;
        Rl[f >> 6][f & 63] = r_matrix[f];
    }

    if (tid < 64) {
        const int t = tid;
        #pragma unroll
        for (int k = 0; k < 64; ++k) M[t][k] = (k == t) ? 1.0f : 0.0f;
        const float scale = theta_scale[0];
        #pragma unroll 1
        for (int r = 0; r < ROT; ++r) {
            const int i = pairs[2 * r + 0];
            const int j = pairs[2 * r + 1];
            const float th = thetas[r] * scale;
            float s, c;
            sincosf(th, &s, &c);
            const float xi = M[t][i];
            const float xj = M[t][j];
            const float gi =  xi * c + xj * s;
            const float gj = -xi * s + xj * c;
            const float ni = (2.0f * gi + xi - 2.0f * gi * c) / 3.0f;
            const float nj = (2.0f * gj + xj - 2.0f * gi * s) / 3.0f;
            M[t][i] = ni;
            M[t][j] = nj;
        }
    }
    __syncthreads();

    // Wp[k][n]: thread (kq = tid>>6, n = tid&63) computes 16 k's for its n.
    const int n = tid & 63;
    const int kq = tid >> 6;
    const int cn = (n < 32) ? (2 * n) : (2 * (n - 32) + 1);
    #pragma unroll 1
    for (int kk = 0; kk < 16; ++kk) {
        const int k = kq * 16 + kk;
        float acc = 0.0f;
        #pragma unroll
        for (int j = 0; j < 64; ++j) acc = fmaf(M[k][j], Rl[j][cn], acc);
        Wp[k * 64 + n] = acc;   // wave-coalesced 256B store
    }
}

// ---------------------------------------------------------------------------
// Main fused kernel: out_row = RoPE_s( x_row @ Wp ).
// 256 threads = 256 rows per block. x staged via LDS (coalesced), W rows
// pulled through the SCALAR pipe (s_load_dwordx16) so weights live in SGPRs.
// ALL acc[] accesses are compile-time-indexed (rule #20) so acc stays in
// VGPRs — the write-back half-loop is explicitly unrolled for this reason.
// ---------------------------------------------------------------------------
__global__ __launch_bounds__(256, 4) void fused_main(
    const float* __restrict__ x,
    const float* __restrict__ Wp,
    const float* __restrict__ inv_freq,
    float* __restrict__ out)
{
    __shared__ float xs[BROWS * PADW];   // 33,792 B
    __shared__ float tc[16 * 33];        // cos table
    __shared__ float tsn[16 * 33];       // sin table

    const int tid = threadIdx.x;
    const int blk = blockIdx.x;
    const long long base4 = (long long)blk * (BROWS * HD / 4);
    const float4* __restrict__ xv = (const float4*)x + base4;
    float4* __restrict__ ov = (float4*)out + base4;

    // trig table for this block's 16 sequence positions
    {
        const int s0 = (blk & (SEQ / 16 - 1)) * 16;
        #pragma unroll
        for (int u = 0; u < 2; ++u) {
            const int e = tid * 2 + u;
            const int sl = e >> 5;
            const int f = e & 31;
            const float ang = (float)(s0 + sl) * inv_freq[f];
            float sn, cs;
            sincosf(ang, &sn, &cs);
            tc[sl * 33 + f] = cs;
            tsn[sl * 33 + f] = sn;
        }
    }

    float acc[64];
    #pragma unroll
    for (int nn = 0; nn < 64; ++nn) acc[nn] = 0.0f;

    #pragma unroll 1
    for (int half = 0; half < 2; ++half) {
        __syncthreads();
        #pragma unroll
        for (int it = 0; it < 8; ++it) {
            const int f = it * 256 + tid;
            const int row = f >> 3;
            const int c4 = f & 7;
            const float4 v = xv[row * 16 + half * 8 + c4];
            float* p = &xs[row * PADW + c4 * 4];
            p[0] = v.x; p[1] = v.y; p[2] = v.z; p[3] = v.w;
        }
        __syncthreads();

        const float* xrow = &xs[tid * PADW];
        #pragma unroll 1
        for (int kc = 0; kc < 2; ++kc) {
            float xk[16];
            #pragma unroll
            for (int m = 0; m < 16; ++m) xk[m] = xrow[kc * 16 + m];
            const int kbase = half * 32 + kc * 16;
            #pragma unroll
            for (int m = 0; m < 16; ++m) {
                // W row (kbase+m): 64 floats via the scalar pipe -> SGPRs
                const float* pm = Wp + (kbase + m) * 64;   // uniform address
                sv16 w0, w1, w2, w3;
                asm volatile(
                    "s_load_dwordx16 %0, %4, 0x0\n\t"
                    "s_load_dwordx16 %1, %4, 0x40\n\t"
                    "s_load_dwordx16 %2, %4, 0x80\n\t"
                    "s_load_dwordx16 %3, %4, 0xC0\n\t"
                    "s_waitcnt lgkmcnt(0)"
                    : "=&s"(w0), "=&s"(w1), "=&s"(w2), "=&s"(w3)
                    : "s"(pm));
                const float xm = xk[m];
                #pragma unroll
                for (int i = 0; i < 16; ++i) {
                    acc[i]      = fmaf(xm, w0[i], acc[i]);
                    acc[16 + i] = fmaf(xm, w1[i], acc[16 + i]);
                    acc[32 + i] = fmaf(xm, w2[i], acc[32 + i]);
                    acc[48 + i] = fmaf(xm, w3[i], acc[48 + i]);
                }
            }
        }
    }

    // RoPE combine: acc[0..31] = even cols, acc[32..63] = odd cols
    {
        const int sl = tid >> 4;
        #pragma unroll
        for (int n = 0; n < 32; ++n) {
            const float c = tc[sl * 33 + n];
            const float s = tsn[sl * 33 + n];
            const float a = acc[n];
            const float b = acc[32 + n];
            acc[n]      = a * c - b * s;
            acc[32 + n] = a * s + b * c;
        }
    }

    // write back through LDS for coalesced stores — TWO EXPLICIT halves so
    // every acc[] index is a compile-time constant (no scratch allocation).
    {
        float* prow = &xs[tid * PADW];
        // ---- half 0: out cols 0..31 = acc[0..31] ----
        __syncthreads();
        #pragma unroll
        for (int n = 0; n < 32; ++n) prow[n] = acc[n];
        __syncthreads();
        #pragma unroll
        for (int it = 0; it < 8; ++it) {
            const int f = it * 256 + tid;
            const int row = f >> 3;
            const int c4 = f & 7;
            const float* p = &xs[row * PADW + c4 * 4];
            ov[row * 16 + c4] = make_float4(p[0], p[1], p[2], p[3]);
        }
        // ---- half 1: out cols 32..63 = acc[32..63] ----
        __syncthreads();
        #pragma unroll
        for (int n = 0; n < 32; ++n) prow[n] = acc[32 + n];
        __syncthreads();
        #pragma unroll
        for (int it = 0; it < 8; ++it) {
            const int f = it * 256 + tid;
            const int row = f >> 3;
            const int c4 = f & 7;
            const float* p = &xs[row * PADW + c4 * 4];
            ov[row * 16 + 8 + c4] = make_float4(p[0], p[1], p[2], p[3]);
        }
    }
}

extern "C" void kernel_launch(void* const* d_in, const int* in_sizes, int n_in,
                              void* d_out, int out_size, void* d_ws, size_t ws_size,
                              hipStream_t stream) {
    const float* x   = (const float*)d_in[0];
    const float* th  = (const float*)d_in[1];
    const float* sc  = (const float*)d_in[2];
    const float* R   = (const float*)d_in[3];
    const float* ivf = (const float*)d_in[4];
    const int*   pr  = (const int*)d_in[5];
    float* W = (float*)d_ws;   // 64*64 floats = 16 KB scratch

    build_W_kernel<<<1, 256, 0, stream>>>(th, sc, R, pr, W);

    const int rows = out_size / HD;        // 524,288
    const int blocks = rows / BROWS;       // 2,048
    fused_main<<<blocks, 256, 0, stream>>>(x, W, ivf, (float*)d_out);
}